// Round 9
// baseline (519.358 us; speedup 1.0000x reference)
//
#include <hip/hip_runtime.h>

#define N_Q   16384
#define C_DIM 128
#define S_CAM 6
#define M_VAL 1400   // 28*50
#define D_Z   8
#define HF    28
#define WF    50
#define QPB   16     // queries per block in the fused kernel (16 lanes/query)

__device__ __forceinline__ float bflo(unsigned u){ return __uint_as_float(u << 16); }
__device__ __forceinline__ float bfhi(unsigned u){ return __uint_as_float(u & 0xffff0000u); }

__device__ __forceinline__ bool mask_any(const unsigned char* __restrict__ mask,
                                         int mflag, size_t mbase){
  if(mflag==0){
    int any=0;
    #pragma unroll
    for(int d=0;d<D_Z;d++) any |= mask[mbase+d];
    return any!=0;
  } else if(mflag==1){
    const int* mp = (const int*)mask;  int any=0;
    #pragma unroll
    for(int d=0;d<D_Z;d++) any |= mp[mbase+d];
    return any!=0;
  } else {
    const long long* mp = (const long long*)mask;  long long any=0;
    #pragma unroll
    for(int d=0;d<D_Z;d++) any |= mp[mbase+d];
    return any!=0;
  }
}

// ---------------------------------------------------------------------------
// v = value @ Wv + bv (8400x128 @ 128x128) -> bf16 workspace.
// 1050 blocks x 256 threads: 8 rows/block. Block 0 piggybacks the bev_mask
// upload-format sniff (0=u8,1=i32,2=i64).
// ---------------------------------------------------------------------------
__global__ __launch_bounds__(256)
void value_proj_kernel(const float* __restrict__ value,
                       const float* __restrict__ Wv,
                       const float* __restrict__ bv,
                       unsigned short* __restrict__ vb16,
                       const unsigned char* __restrict__ mask,
                       int* __restrict__ flag){
  __shared__ float tile[8][C_DIM];
  __shared__ int s_cntA, s_cntB;
  const int tid = threadIdx.x;
  const int col = tid & 127;
  const int rh  = tid >> 7;                    // rows rh*4 .. rh*4+3
  const int r0  = blockIdx.x * 8;
  if(blockIdx.x==0 && tid==0){ s_cntA=0; s_cntB=0; }
  {
    const float4* src = (const float4*)(value + (size_t)r0*C_DIM);
    ((float4*)&tile[0][0])[tid] = src[tid];
  }
  __syncthreads();
  float acc[4];
  const float bias = bv[col];
  #pragma unroll
  for(int r=0;r<4;r++) acc[r]=bias;
  for(int k=0;k<C_DIM;k+=4){
    const float w0 = Wv[(k+0)*C_DIM + col];
    const float w1 = Wv[(k+1)*C_DIM + col];
    const float w2 = Wv[(k+2)*C_DIM + col];
    const float w3 = Wv[(k+3)*C_DIM + col];
    #pragma unroll
    for(int r=0;r<4;r++){
      const float4 t = *(const float4*)&tile[rh*4+r][k];
      acc[r] += t.x*w0 + t.y*w1 + t.z*w2 + t.w*w3;
    }
  }
  #pragma unroll
  for(int r=0;r<4;r++){
    unsigned u = __float_as_uint(acc[r]);
    u += 0x7fff + ((u >> 16) & 1);             // RNE bf16
    vb16[(size_t)(r0+rh*4+r)*C_DIM + col] = (unsigned short)(u >> 16);
  }
  if(blockIdx.x==0){
    int a=0, b=0;
    for(int i=tid;i<1024;i+=256){
      const unsigned char v = mask[i];
      if(((i&3)!=0) && v) a=1;
      if(((i&7)==4) && v) b=1;
    }
    if(a) atomicOr(&s_cntA,1);
    if(b) atomicOr(&s_cntB,1);
    __syncthreads();
    if(tid==0) flag[0] = s_cntA ? 0 : (s_cntB ? 1 : 2);
  }
}

// ---------------------------------------------------------------------------
// Fused deformable attention, 16 lanes/query (8 channels/lane, uint4 16-B
// gathers). Gather region is barrier-free: coordinate math recomputed per
// lane from LDS broadcasts, amortized over 8 channels (vs 4 in round 8 ->
// total coord VALU halves; loads half count, double width).
// launch_bounds(256,4): 128-VGPR budget, spill-free lineage.
// ---------------------------------------------------------------------------
__global__ __launch_bounds__(256, 4)
void fused_deform_kernel(const unsigned short* __restrict__ vb16,
                         const float* __restrict__ query,
                         const float* __restrict__ query_pos,
                         const float* __restrict__ Wo, const float* __restrict__ bo,
                         const float* __restrict__ Wa, const float* __restrict__ ba,
                         const float* __restrict__ ref,
                         const unsigned char* __restrict__ mask,
                         const int* __restrict__ flag,
                         const float* __restrict__ Wout,
                         const float* __restrict__ bout,
                         float* __restrict__ out){
  __shared__ float  qs[QPB][C_DIM+4];        // q staging; reused as slots (132 mod 32 = 4)
  __shared__ float  offs[QPB][68];           // 68 mod 32 = 4
  __shared__ float  attns[QPB][36];          // 36 mod 32 = 4
  __shared__ float  logits[QPB][36];
  __shared__ float2 refs[QPB][S_CAM*D_Z+1];  // 49 f2 rows = 98 f, mod 32 = 2
  __shared__ int    activ[QPB][S_CAM];
  __shared__ float  cinv[QPB];

  const int tid = threadIdx.x;
  const int n0  = blockIdx.x * QPB;
  const int mflag = flag[0];
  const int qi = tid >> 4;                   // query in block (0..15)
  const int l  = tid & 15;                   // lane within query group

  // ---- 0) issue ref prefetch (768 float2 entries; 3 per thread) ----
  float2 rpre[3];
  #pragma unroll
  for(int j=0;j<3;j++){
    const int e = tid + 256*j;               // e -> q=e/48, s=(e%48)/8, p=e%8
    const int q = e/48, r = e%48;
    rpre[j] = ((const float2*)ref)[((size_t)(r>>3)*N_Q + (n0+q))*D_Z + (r&7)];
  }

  // ---- 1) q = query + query_pos ----
  {
    const float4* qa = (const float4*)(query     + (size_t)n0*C_DIM);
    const float4* qb = (const float4*)(query_pos + (size_t)n0*C_DIM);
    #pragma unroll
    for(int j=0;j<2;j++){
      const int idx = tid + 256*j;
      const int r = idx >> 5, c4 = idx & 31;
      float4 A = qa[idx], B = qb[idx];
      *(float4*)&qs[r][c4*4] = make_float4(A.x+B.x, A.y+B.y, A.z+B.z, A.w+B.w);
    }
  }
  __syncthreads();

  // ---- 2) projections: lane l -> off cols l*4..l*4+3, logit cols l*2..l*2+1 ----
  {
    float ao0 = bo[l*4+0], ao1 = bo[l*4+1], ao2 = bo[l*4+2], ao3 = bo[l*4+3];
    float aa0 = ba[l*2+0], aa1 = ba[l*2+1];
    for(int k=0;k<C_DIM;k++){
      const float qv = qs[qi][k];
      const float4 wo = *(const float4*)&Wo[k*64 + l*4];
      const float2 wa = *(const float2*)&Wa[k*32 + l*2];
      ao0 += qv*wo.x; ao1 += qv*wo.y; ao2 += qv*wo.z; ao3 += qv*wo.w;
      aa0 += qv*wa.x; aa1 += qv*wa.y;
    }
    offs[qi][l*4+0] = ao0;  offs[qi][l*4+1] = ao1;
    offs[qi][l*4+2] = ao2;  offs[qi][l*4+3] = ao3;
    logits[qi][l*2+0] = aa0;  logits[qi][l*2+1] = aa1;
  }
  #pragma unroll
  for(int j=0;j<3;j++){
    const int e = tid + 256*j;
    refs[e/48][e%48] = rpre[j];
  }
  if(tid < QPB*S_CAM){
    const int q2 = tid / S_CAM, s = tid % S_CAM;
    activ[q2][s] = mask_any(mask, mflag, ((size_t)s*N_Q + (n0+q2))*D_Z) ? 1 : 0;
  }
  __syncthreads();
  if(tid < 64){                              // softmax over P=8: (q2, h)
    const int q2 = tid >> 2, h = tid & 3;
    const float* L = &logits[q2][h*8];
    float mx = L[0];
    #pragma unroll
    for(int p=1;p<8;p++) mx = fmaxf(mx, L[p]);
    float e[8], ssum = 0.f;
    #pragma unroll
    for(int p=0;p<8;p++){ e[p] = __expf(L[p]-mx); ssum += e[p]; }
    const float inv = 1.f/ssum;
    #pragma unroll
    for(int p=0;p<8;p++) attns[q2][h*8+p] = e[p]*inv;
  } else if(tid >= 256-QPB){
    const int q2 = tid - (256-QPB);
    int c = 0;
    #pragma unroll
    for(int s=0;s<S_CAM;s++) c += activ[q2][s];
    cinv[q2] = 1.f / fmaxf((float)c, 1.f);
  }
  __syncthreads();

  // ---- 3) barrier-free gather: lane = (qi, h, 8ch) ----
  const int gh  = l >> 2;                    // head (4 lanes/head)
  const int gch = gh*32 + (l&3)*8;           // first of 8 channels
  float a0=0.f,a1=0.f,a2=0.f,a3=0.f,a4=0.f,a5=0.f,a6=0.f,a7=0.f;

  for(int s=0;s<S_CAM;s++){
    if(!activ[qi][s]) continue;
    const unsigned short* vb = vb16 + (size_t)s*M_VAL*C_DIM + gch;
    #pragma unroll
    for(int p=0;p<8;p++){                    // point p <-> z-anchor d=p (P//D==1)
      const float2 r2 = refs[qi][s*8+p];
      const float ox = offs[qi][gh*16+p*2+0];
      const float oy = offs[qi][gh*16+p*2+1];
      const float x = fmaf(r2.x, (float)WF, ox - 0.5f);
      const float y = fmaf(r2.y, (float)HF, oy - 0.5f);
      const float x0f = floorf(x), y0f = floorf(y);
      const float fx = x - x0f,    fy = y - y0f;
      const int x0 = (int)x0f, y0 = (int)y0f;
      const int x1 = x0+1,     y1 = y0+1;
      const float at = attns[qi][gh*8+p];
      const float wx0 = (x0>=0 && x0<WF) ? (1.f-fx) : 0.f;
      const float wx1 = (x1>=0 && x1<WF) ? fx       : 0.f;
      const float wy0 = ((y0>=0 && y0<HF) ? (1.f-fy) : 0.f) * at;
      const float wy1 = ((y1>=0 && y1<HF) ? fy       : 0.f) * at;
      const int x0c = min(max(x0,0), WF-1), x1c = min(max(x1,0), WF-1);
      const int y0c = min(max(y0,0), HF-1), y1c = min(max(y1,0), HF-1);
      const float w00 = wx0*wy0, w01 = wx1*wy0, w10 = wx0*wy1, w11 = wx1*wy1;
      const uint4 v00 = *(const uint4*)(vb + (y0c*WF+x0c)*C_DIM);
      const uint4 v01 = *(const uint4*)(vb + (y0c*WF+x1c)*C_DIM);
      const uint4 v10 = *(const uint4*)(vb + (y1c*WF+x0c)*C_DIM);
      const uint4 v11 = *(const uint4*)(vb + (y1c*WF+x1c)*C_DIM);
      a0 += w00*bflo(v00.x) + w01*bflo(v01.x) + w10*bflo(v10.x) + w11*bflo(v11.x);
      a1 += w00*bfhi(v00.x) + w01*bfhi(v01.x) + w10*bfhi(v10.x) + w11*bfhi(v11.x);
      a2 += w00*bflo(v00.y) + w01*bflo(v01.y) + w10*bflo(v10.y) + w11*bflo(v11.y);
      a3 += w00*bfhi(v00.y) + w01*bfhi(v01.y) + w10*bfhi(v10.y) + w11*bfhi(v11.y);
      a4 += w00*bflo(v00.z) + w01*bflo(v01.z) + w10*bflo(v10.z) + w11*bflo(v11.z);
      a5 += w00*bfhi(v00.z) + w01*bfhi(v01.z) + w10*bfhi(v10.z) + w11*bfhi(v11.z);
      a6 += w00*bflo(v00.w) + w01*bflo(v01.w) + w10*bflo(v10.w) + w11*bflo(v11.w);
      a7 += w00*bfhi(v00.w) + w01*bfhi(v01.w) + w10*bfhi(v10.w) + w11*bfhi(v11.w);
    }
  }

  // ---- 4) slots (reuse qs) -> out-proj + residual ----
  __syncthreads();
  {
    const float inv = cinv[qi];
    *(float4*)&qs[qi][gch]   = make_float4(a0*inv, a1*inv, a2*inv, a3*inv);
    *(float4*)&qs[qi][gch+4] = make_float4(a4*inv, a5*inv, a6*inv, a7*inv);
  }
  __syncthreads();
  {
    const int c0 = l*8;                      // 8 output cols per lane
    const int n  = n0 + qi;
    const float4 bA = *(const float4*)&bout[c0];
    const float4 bB = *(const float4*)&bout[c0+4];
    const float4 rA = *(const float4*)&query[(size_t)n*C_DIM + c0];
    const float4 rB = *(const float4*)&query[(size_t)n*C_DIM + c0 + 4];
    float o0=bA.x+rA.x, o1=bA.y+rA.y, o2=bA.z+rA.z, o3=bA.w+rA.w;
    float o4=bB.x+rB.x, o5=bB.y+rB.y, o6=bB.z+rB.z, o7=bB.w+rB.w;
    for(int k=0;k<C_DIM;k++){
      const float sv = qs[qi][k];
      const float4 wA = *(const float4*)&Wout[(size_t)k*C_DIM + c0];
      const float4 wB = *(const float4*)&Wout[(size_t)k*C_DIM + c0 + 4];
      o0 += sv*wA.x; o1 += sv*wA.y; o2 += sv*wA.z; o3 += sv*wA.w;
      o4 += sv*wB.x; o5 += sv*wB.y; o6 += sv*wB.z; o7 += sv*wB.w;
    }
    *(float4*)&out[(size_t)n*C_DIM + c0]     = make_float4(o0,o1,o2,o3);
    *(float4*)&out[(size_t)n*C_DIM + c0 + 4] = make_float4(o4,o5,o6,o7);
  }
}

extern "C" void kernel_launch(void* const* d_in, const int* in_sizes, int n_in,
                              void* d_out, int out_size, void* d_ws, size_t ws_size,
                              hipStream_t stream){
  const float* query     = (const float*)d_in[0];
  const float* query_pos = (const float*)d_in[1];
  const float* value     = (const float*)d_in[2];
  const float* ref       = (const float*)d_in[3];
  const unsigned char* mask = (const unsigned char*)d_in[4];
  const float* Wv   = (const float*)d_in[5];
  const float* bv   = (const float*)d_in[6];
  const float* Wo   = (const float*)d_in[7];
  const float* bo   = (const float*)d_in[8];
  const float* Wa   = (const float*)d_in[9];
  const float* ba   = (const float*)d_in[10];
  const float* Wout = (const float*)d_in[11];
  const float* bout = (const float*)d_in[12];
  float* out = (float*)d_out;

  int* flag = (int*)d_ws;
  unsigned short* vb16 = (unsigned short*)((char*)d_ws + 64);

  value_proj_kernel<<<(S_CAM*M_VAL)/8, 256, 0, stream>>>(value, Wv, bv, vb16, mask, flag);
  fused_deform_kernel<<<N_Q/QPB, 256, 0, stream>>>(vb16, query, query_pos,
                                                   Wo, bo, Wa, ba, ref, mask, flag,
                                                   Wout, bout, out);
}

// Round 10
// 193.528 us; speedup vs baseline: 2.6836x; 2.6836x over previous
//
#include <hip/hip_runtime.h>
#include <hip/hip_fp16.h>

#define N_Q   16384
#define C_DIM 128
#define S_CAM 6
#define M_VAL 1400   // 28*50
#define D_Z   8
#define HF    28
#define WF    50
#define QPB   16     // queries per block in the fused kernel (16 lanes/query)

__device__ __forceinline__ bool mask_any(const unsigned char* __restrict__ mask,
                                         int mflag, size_t mbase){
  if(mflag==0){
    int any=0;
    #pragma unroll
    for(int d=0;d<D_Z;d++) any |= mask[mbase+d];
    return any!=0;
  } else if(mflag==1){
    const int* mp = (const int*)mask;  int any=0;
    #pragma unroll
    for(int d=0;d<D_Z;d++) any |= mp[mbase+d];
    return any!=0;
  } else {
    const long long* mp = (const long long*)mask;  long long any=0;
    #pragma unroll
    for(int d=0;d<D_Z;d++) any |= mp[mbase+d];
    return any!=0;
  }
}

// ---------------------------------------------------------------------------
// v = value @ Wv + bv (8400x128 @ 128x128) -> FP16 workspace (for v_pk_fma_f16
// gather: no unpack instructions, 3 more mantissa bits than bf16).
// 1050 blocks x 256 threads: 8 rows/block. Block 0 piggybacks the bev_mask
// upload-format sniff (0=u8,1=i32,2=i64).
// ---------------------------------------------------------------------------
__global__ __launch_bounds__(256)
void value_proj_kernel(const float* __restrict__ value,
                       const float* __restrict__ Wv,
                       const float* __restrict__ bv,
                       unsigned short* __restrict__ vh16,
                       const unsigned char* __restrict__ mask,
                       int* __restrict__ flag){
  __shared__ float tile[8][C_DIM];
  __shared__ int s_cntA, s_cntB;
  const int tid = threadIdx.x;
  const int col = tid & 127;
  const int rh  = tid >> 7;                    // rows rh*4 .. rh*4+3
  const int r0  = blockIdx.x * 8;
  if(blockIdx.x==0 && tid==0){ s_cntA=0; s_cntB=0; }
  {
    const float4* src = (const float4*)(value + (size_t)r0*C_DIM);
    ((float4*)&tile[0][0])[tid] = src[tid];
  }
  __syncthreads();
  float acc[4];
  const float bias = bv[col];
  #pragma unroll
  for(int r=0;r<4;r++) acc[r]=bias;
  for(int k=0;k<C_DIM;k+=4){
    const float w0 = Wv[(k+0)*C_DIM + col];
    const float w1 = Wv[(k+1)*C_DIM + col];
    const float w2 = Wv[(k+2)*C_DIM + col];
    const float w3 = Wv[(k+3)*C_DIM + col];
    #pragma unroll
    for(int r=0;r<4;r++){
      const float4 t = *(const float4*)&tile[rh*4+r][k];
      acc[r] += t.x*w0 + t.y*w1 + t.z*w2 + t.w*w3;
    }
  }
  #pragma unroll
  for(int r=0;r<4;r++)
    vh16[(size_t)(r0+rh*4+r)*C_DIM + col] =
        __half_as_ushort(__float2half_rn(acc[r]));
  if(blockIdx.x==0){
    int a=0, b=0;
    for(int i=tid;i<1024;i+=256){
      const unsigned char v = mask[i];
      if(((i&3)!=0) && v) a=1;
      if(((i&7)==4) && v) b=1;
    }
    if(a) atomicOr(&s_cntA,1);
    if(b) atomicOr(&s_cntB,1);
    __syncthreads();
    if(tid==0) flag[0] = s_cntA ? 0 : (s_cntB ? 1 : 2);
  }
}

// ---------------------------------------------------------------------------
// Fused deformable attention, 16 lanes/query, 8 channels/lane.
// Gather: fp16 uint4 (16B) corner loads -> 4x __hfma2 each (v_pk_fma_f16,
// no unpack). Point loop unroll(2) to cap live load registers (round 9's
// full unroll spilled 918 MB). __launch_bounds__(256) only: every forced
// VGPR cap so far has spilled (32->343MB, 85->55MB, implicit 64->918MB).
// ---------------------------------------------------------------------------
__global__ __launch_bounds__(256)
void fused_deform_kernel(const unsigned short* __restrict__ vh16,
                         const float* __restrict__ query,
                         const float* __restrict__ query_pos,
                         const float* __restrict__ Wo, const float* __restrict__ bo,
                         const float* __restrict__ Wa, const float* __restrict__ ba,
                         const float* __restrict__ ref,
                         const unsigned char* __restrict__ mask,
                         const int* __restrict__ flag,
                         const float* __restrict__ Wout,
                         const float* __restrict__ bout,
                         float* __restrict__ out){
  __shared__ float  qs[QPB][C_DIM+4];        // q staging; reused as slots
  __shared__ float  offs[QPB][68];           // 68 mod 32 = 4
  __shared__ float  attns[QPB][36];
  __shared__ float  logits[QPB][36];
  __shared__ float2 refs[QPB][S_CAM*D_Z+1];  // 49 f2 rows: 98 mod 32 = 2
  __shared__ int    activ[QPB][S_CAM];
  __shared__ float  cinv[QPB];

  const int tid = threadIdx.x;
  const int n0  = blockIdx.x * QPB;
  const int mflag = flag[0];
  const int qi = tid >> 4;                   // query in block (0..15)
  const int l  = tid & 15;                   // lane within query group

  // ---- 0) ref prefetch (768 float2; 3/thread) ----
  float2 rpre[3];
  #pragma unroll
  for(int j=0;j<3;j++){
    const int e = tid + 256*j;               // e -> q=e/48, s=(e%48)/8, p=e%8
    const int q = e/48, r = e%48;
    rpre[j] = ((const float2*)ref)[((size_t)(r>>3)*N_Q + (n0+q))*D_Z + (r&7)];
  }

  // ---- 1) q = query + query_pos ----
  {
    const float4* qa = (const float4*)(query     + (size_t)n0*C_DIM);
    const float4* qb = (const float4*)(query_pos + (size_t)n0*C_DIM);
    #pragma unroll
    for(int j=0;j<2;j++){
      const int idx = tid + 256*j;
      const int r = idx >> 5, c4 = idx & 31;
      float4 A = qa[idx], B = qb[idx];
      *(float4*)&qs[r][c4*4] = make_float4(A.x+B.x, A.y+B.y, A.z+B.z, A.w+B.w);
    }
  }
  __syncthreads();

  // ---- 2) projections: lane l -> off cols l*4.., logit cols l*2.. ----
  {
    float ao0 = bo[l*4+0], ao1 = bo[l*4+1], ao2 = bo[l*4+2], ao3 = bo[l*4+3];
    float aa0 = ba[l*2+0], aa1 = ba[l*2+1];
    for(int k=0;k<C_DIM;k++){
      const float qv = qs[qi][k];
      const float4 wo = *(const float4*)&Wo[k*64 + l*4];
      const float2 wa = *(const float2*)&Wa[k*32 + l*2];
      ao0 += qv*wo.x; ao1 += qv*wo.y; ao2 += qv*wo.z; ao3 += qv*wo.w;
      aa0 += qv*wa.x; aa1 += qv*wa.y;
    }
    offs[qi][l*4+0] = ao0;  offs[qi][l*4+1] = ao1;
    offs[qi][l*4+2] = ao2;  offs[qi][l*4+3] = ao3;
    logits[qi][l*2+0] = aa0;  logits[qi][l*2+1] = aa1;
  }
  #pragma unroll
  for(int j=0;j<3;j++){
    const int e = tid + 256*j;
    refs[e/48][e%48] = rpre[j];
  }
  if(tid < QPB*S_CAM){
    const int q2 = tid / S_CAM, s = tid % S_CAM;
    activ[q2][s] = mask_any(mask, mflag, ((size_t)s*N_Q + (n0+q2))*D_Z) ? 1 : 0;
  }
  __syncthreads();
  if(tid < 64){                              // softmax over P=8: (q2, h)
    const int q2 = tid >> 2, h = tid & 3;
    const float* L = &logits[q2][h*8];
    float mx = L[0];
    #pragma unroll
    for(int p=1;p<8;p++) mx = fmaxf(mx, L[p]);
    float e[8], ssum = 0.f;
    #pragma unroll
    for(int p=0;p<8;p++){ e[p] = __expf(L[p]-mx); ssum += e[p]; }
    const float inv = 1.f/ssum;
    #pragma unroll
    for(int p=0;p<8;p++) attns[q2][h*8+p] = e[p]*inv;
  } else if(tid >= 256-QPB){
    const int q2 = tid - (256-QPB);
    int c = 0;
    #pragma unroll
    for(int s=0;s<S_CAM;s++) c += activ[q2][s];
    cinv[q2] = 1.f / fmaxf((float)c, 1.f);
  }
  __syncthreads();

  // ---- 3) barrier-free gather: lane = (qi, h, 8ch), packed-fp16 FMA ----
  const int gh  = l >> 2;                    // head (4 lanes/head)
  const int gch = gh*32 + (l&3)*8;           // first of 8 channels
  __half2 acc0 = __float2half2_rn(0.f);
  __half2 acc1 = acc0, acc2 = acc0, acc3 = acc0;

  for(int s=0;s<S_CAM;s++){
    if(!activ[qi][s]) continue;
    const unsigned short* vb = vh16 + (size_t)s*M_VAL*C_DIM + gch;
    #pragma unroll 2
    for(int p=0;p<8;p++){                    // point p <-> z-anchor d=p (P//D==1)
      const float2 r2 = refs[qi][s*8+p];
      const float ox = offs[qi][gh*16+p*2+0];
      const float oy = offs[qi][gh*16+p*2+1];
      const float x = fmaf(r2.x, (float)WF, ox - 0.5f);
      const float y = fmaf(r2.y, (float)HF, oy - 0.5f);
      const float x0f = floorf(x), y0f = floorf(y);
      const float fx = x - x0f,    fy = y - y0f;
      const int x0 = (int)x0f, y0 = (int)y0f;
      const int x1 = x0+1,     y1 = y0+1;
      const float at = attns[qi][gh*8+p];
      const float wx0 = (x0>=0 && x0<WF) ? (1.f-fx) : 0.f;
      const float wx1 = (x1>=0 && x1<WF) ? fx       : 0.f;
      const float wy0 = ((y0>=0 && y0<HF) ? (1.f-fy) : 0.f) * at;
      const float wy1 = ((y1>=0 && y1<HF) ? fy       : 0.f) * at;
      const int x0c = min(max(x0,0), WF-1), x1c = min(max(x1,0), WF-1);
      const int y0c = min(max(y0,0), HF-1), y1c = min(max(y1,0), HF-1);
      const __half2 W00 = __float2half2_rn(wx0*wy0);
      const __half2 W01 = __float2half2_rn(wx1*wy0);
      const __half2 W10 = __float2half2_rn(wx0*wy1);
      const __half2 W11 = __float2half2_rn(wx1*wy1);
      const uint4 v00 = *(const uint4*)(vb + (y0c*WF+x0c)*C_DIM);
      const uint4 v01 = *(const uint4*)(vb + (y0c*WF+x1c)*C_DIM);
      const uint4 v10 = *(const uint4*)(vb + (y1c*WF+x0c)*C_DIM);
      const uint4 v11 = *(const uint4*)(vb + (y1c*WF+x1c)*C_DIM);
      #define H2(u) (*reinterpret_cast<const __half2*>(&(u)))
      acc0 = __hfma2(H2(v00.x), W00, acc0);  acc0 = __hfma2(H2(v01.x), W01, acc0);
      acc0 = __hfma2(H2(v10.x), W10, acc0);  acc0 = __hfma2(H2(v11.x), W11, acc0);
      acc1 = __hfma2(H2(v00.y), W00, acc1);  acc1 = __hfma2(H2(v01.y), W01, acc1);
      acc1 = __hfma2(H2(v10.y), W10, acc1);  acc1 = __hfma2(H2(v11.y), W11, acc1);
      acc2 = __hfma2(H2(v00.z), W00, acc2);  acc2 = __hfma2(H2(v01.z), W01, acc2);
      acc2 = __hfma2(H2(v10.z), W10, acc2);  acc2 = __hfma2(H2(v11.z), W11, acc2);
      acc3 = __hfma2(H2(v00.w), W00, acc3);  acc3 = __hfma2(H2(v01.w), W01, acc3);
      acc3 = __hfma2(H2(v10.w), W10, acc3);  acc3 = __hfma2(H2(v11.w), W11, acc3);
      #undef H2
    }
  }

  // ---- 4) slots (reuse qs) -> out-proj + residual ----
  __syncthreads();
  {
    const float inv = cinv[qi];
    *(float4*)&qs[qi][gch]   = make_float4(__low2float(acc0)*inv, __high2float(acc0)*inv,
                                           __low2float(acc1)*inv, __high2float(acc1)*inv);
    *(float4*)&qs[qi][gch+4] = make_float4(__low2float(acc2)*inv, __high2float(acc2)*inv,
                                           __low2float(acc3)*inv, __high2float(acc3)*inv);
  }
  __syncthreads();
  {
    const int c0 = l*8;                      // 8 output cols per lane
    const int n  = n0 + qi;
    const float4 bA = *(const float4*)&bout[c0];
    const float4 bB = *(const float4*)&bout[c0+4];
    const float4 rA = *(const float4*)&query[(size_t)n*C_DIM + c0];
    const float4 rB = *(const float4*)&query[(size_t)n*C_DIM + c0 + 4];
    float o0=bA.x+rA.x, o1=bA.y+rA.y, o2=bA.z+rA.z, o3=bA.w+rA.w;
    float o4=bB.x+rB.x, o5=bB.y+rB.y, o6=bB.z+rB.z, o7=bB.w+rB.w;
    for(int k=0;k<C_DIM;k++){
      const float sv = qs[qi][k];
      const float4 wA = *(const float4*)&Wout[(size_t)k*C_DIM + c0];
      const float4 wB = *(const float4*)&Wout[(size_t)k*C_DIM + c0 + 4];
      o0 += sv*wA.x; o1 += sv*wA.y; o2 += sv*wA.z; o3 += sv*wA.w;
      o4 += sv*wB.x; o5 += sv*wB.y; o6 += sv*wB.z; o7 += sv*wB.w;
    }
    *(float4*)&out[(size_t)n*C_DIM + c0]     = make_float4(o0,o1,o2,o3);
    *(float4*)&out[(size_t)n*C_DIM + c0 + 4] = make_float4(o4,o5,o6,o7);
  }
}

extern "C" void kernel_launch(void* const* d_in, const int* in_sizes, int n_in,
                              void* d_out, int out_size, void* d_ws, size_t ws_size,
                              hipStream_t stream){
  const float* query     = (const float*)d_in[0];
  const float* query_pos = (const float*)d_in[1];
  const float* value     = (const float*)d_in[2];
  const float* ref       = (const float*)d_in[3];
  const unsigned char* mask = (const unsigned char*)d_in[4];
  const float* Wv   = (const float*)d_in[5];
  const float* bv   = (const float*)d_in[6];
  const float* Wo   = (const float*)d_in[7];
  const float* bo   = (const float*)d_in[8];
  const float* Wa   = (const float*)d_in[9];
  const float* ba   = (const float*)d_in[10];
  const float* Wout = (const float*)d_in[11];
  const float* bout = (const float*)d_in[12];
  float* out = (float*)d_out;

  int* flag = (int*)d_ws;
  unsigned short* vh16 = (unsigned short*)((char*)d_ws + 64);

  value_proj_kernel<<<(S_CAM*M_VAL)/8, 256, 0, stream>>>(value, Wv, bv, vh16, mask, flag);
  fused_deform_kernel<<<N_Q/QPB, 256, 0, stream>>>(vh16, query, query_pos,
                                                   Wo, bo, Wa, ba, ref, mask, flag,
                                                   Wout, bout, out);
}